// Round 1
// baseline (494.821 us; speedup 1.0000x reference)
//
#include <hip/hip_runtime.h>

// ---------------------------------------------------------------------------
// GLMAttention: qkv proj (+RoPE) -> fused flash attn (scores out + softmax+PV)
// -> output proj.  All matmuls fp16 MFMA (16x16x32), f32 accumulate.
// B=4 S=1024 HID=2048 H=16 D=128. Needs ws_size >= ~135 MB.
// ---------------------------------------------------------------------------

#define B_  4
#define S_  1024
#define HID_ 2048
#define H_  16
#define D_  128
#define M_  (B_ * S_)      // 4096 tokens
#define RSQRT_D 0.08838834764831845f

typedef _Float16 f16x8 __attribute__((ext_vector_type(8)));
typedef float f32x4 __attribute__((ext_vector_type(4)));

#define MFMA16(a, b, c) __builtin_amdgcn_mfma_f32_16x16x32_f16(a, b, c, 0, 0, 0)

__device__ __forceinline__ void gll16(const void* g, void* l) {
  __builtin_amdgcn_global_load_lds(
      (const __attribute__((address_space(1))) void*)g,
      (__attribute__((address_space(3))) void*)l, 16, 0, 0);
}

// ---------------------------------------------------------------------------
// RoPE tables: cos/sin[pos][j], j in [0,32), inv_freq = 10000^(-j/32)
// ---------------------------------------------------------------------------
__global__ void rope_table_kernel(float* __restrict__ tcos, float* __restrict__ tsin) {
  int i = blockIdx.x * blockDim.x + threadIdx.x;  // 32768 = 1024*32
  int pos = i >> 5, j = i & 31;
  float inv = expf(-(float)j * (9.210340371976184f / 32.0f));  // ln(10000)/32
  float ang = (float)pos * inv;
  tcos[i] = cosf(ang);
  tsin[i] = sinf(ang);
}

// ---------------------------------------------------------------------------
// f32 -> f16 convert, 8 elems/thread, vectorized
// ---------------------------------------------------------------------------
__global__ void cvt_kernel(const float* __restrict__ in, _Float16* __restrict__ out, int n8) {
  int i = blockIdx.x * blockDim.x + threadIdx.x;
  if (i >= n8) return;
  const float4* in4 = (const float4*)in;
  float4 a = in4[i * 2], b = in4[i * 2 + 1];
  f16x8 v;
  v[0] = (_Float16)a.x; v[1] = (_Float16)a.y; v[2] = (_Float16)a.z; v[3] = (_Float16)a.w;
  v[4] = (_Float16)b.x; v[5] = (_Float16)b.y; v[6] = (_Float16)b.z; v[7] = (_Float16)b.w;
  *(f16x8*)(out + (size_t)i * 8) = v;
}

// ---------------------------------------------------------------------------
// GEMM: C = A(MxK) @ W(NxK)^T + bias.  128x128 tile, BK=64, 4 waves, 4x4 frags.
// MODE 0: RoPE epilogue  -> f16 out (B,H,S,D)
// MODE 1: plain head     -> f16 out (B,H,S,D)
// MODE 2: f32 + bias     -> f32 out (M,N)  (final output)
// ---------------------------------------------------------------------------
template <int MODE>
__global__ __launch_bounds__(256) void proj_kernel(
    const _Float16* __restrict__ A, const _Float16* __restrict__ Bw,
    const float* __restrict__ bias, void* __restrict__ outp,
    const int* __restrict__ pids, const float* __restrict__ tcos,
    const float* __restrict__ tsin) {
  constexpr int N = HID_, K = HID_;
  constexpr int BK = 64;
  __shared__ _Float16 As[128 * BK];
  __shared__ _Float16 Bs[128 * BK];

  const int tid = threadIdx.x;
  // XCD-aware swizzle (512 blocks, 512%8==0 -> bijective)
  const int bid = (blockIdx.x & 7) * 64 + (blockIdx.x >> 3);
  const int tm = bid >> 4, tn = bid & 15;  // 32 x 16 tiles
  const int m0 = tm * 128, n0 = tn * 128;
  const int w = tid >> 6, l = tid & 63;
  const int mw = (w >> 1) * 64, nw = (w & 1) * 64;
  const int lr = l & 15, lh = l >> 4;

  f32x4 acc[4][4] = {};

  for (int kt = 0; kt < K / BK; ++kt) {
    const int k0 = kt * BK;
    __syncthreads();
#pragma unroll
    for (int i = 0; i < 4; ++i) {
      const int e = i * 2048 + tid * 8;
      gll16(A + (size_t)(m0 + (e >> 6)) * K + k0 + (e & 63), As + e);
      gll16(Bw + (size_t)(n0 + (e >> 6)) * K + k0 + (e & 63), Bs + e);
    }
    asm volatile("s_waitcnt vmcnt(0)" ::: "memory");
    __syncthreads();
#pragma unroll
    for (int kk = 0; kk < 2; ++kk) {
      f16x8 af[4], bf[4];
#pragma unroll
      for (int mi = 0; mi < 4; ++mi)
        af[mi] = *(const f16x8*)(As + (mw + mi * 16 + lr) * BK + kk * 32 + lh * 8);
#pragma unroll
      for (int ni = 0; ni < 4; ++ni)
        bf[ni] = *(const f16x8*)(Bs + (nw + ni * 16 + lr) * BK + kk * 32 + lh * 8);
#pragma unroll
      for (int mi = 0; mi < 4; ++mi)
#pragma unroll
        for (int ni = 0; ni < 4; ++ni)
          acc[mi][ni] = MFMA16(af[mi], bf[ni], acc[mi][ni]);
    }
  }

  if constexpr (MODE == 2) {
    float* out = (float*)outp;
#pragma unroll
    for (int mi = 0; mi < 4; ++mi)
#pragma unroll
      for (int ni = 0; ni < 4; ++ni) {
        const int col = n0 + nw + ni * 16 + lr;
        const float bb = bias[col];
#pragma unroll
        for (int r = 0; r < 4; ++r) {
          const int row = m0 + mw + mi * 16 + lh * 4 + r;
          out[(size_t)row * N + col] = acc[mi][ni][r] + bb;
        }
      }
  } else if constexpr (MODE == 1) {
    _Float16* out = (_Float16*)outp;
#pragma unroll
    for (int mi = 0; mi < 4; ++mi)
#pragma unroll
      for (int ni = 0; ni < 4; ++ni) {
        const int col = n0 + nw + ni * 16 + lr;
        const float bb = bias[col];
        const int h = col >> 7, hd = col & 127;
#pragma unroll
        for (int r = 0; r < 4; ++r) {
          const int row = m0 + mw + mi * 16 + lh * 4 + r;
          const int b = row >> 10, s = row & 1023;
          out[(((size_t)(b * H_ + h)) * S_ + s) * D_ + hd] = (_Float16)(acc[mi][ni][r] + bb);
        }
      }
  } else {  // MODE 0: RoPE. wave covers cols [c0,c0+64) = head dims [0,64) or [64,128)
    _Float16* out = (_Float16*)outp;
    const int sel = (nw >> 6) & 1;  // 0 -> pid row, 1 -> bid row of position_ids
#pragma unroll
    for (int mi = 0; mi < 4; ++mi) {
#pragma unroll
      for (int r = 0; r < 4; ++r) {
        const int row = m0 + mw + mi * 16 + lh * 4 + r;
        const int b = row >> 10, s = row & 1023;
        const int pos = pids[b * 2 * S_ + sel * S_ + s];
#pragma unroll
        for (int ni = 0; ni < 2; ++ni) {
          const int col = n0 + nw + ni * 16 + lr;  // first of (d, d+32) pair
          const int j = ni * 16 + lr;              // 0..31 freq index
          const float c = tcos[pos * 32 + j];
          const float sn = tsin[pos * 32 + j];
          const float x1 = acc[mi][ni][r] + bias[col];
          const float x2 = acc[mi][ni + 2][r] + bias[col + 32];
          const int h = col >> 7, hd = col & 127;
          const size_t base = (((size_t)(b * H_ + h)) * S_ + s) * D_;
          out[base + hd] = (_Float16)(x1 * c - x2 * sn);
          out[base + hd + 32] = (_Float16)(x2 * c + x1 * sn);
        }
      }
    }
  }
}

// ---------------------------------------------------------------------------
// V transpose: (B,H,S,D) -> (B,H,D,S)
// ---------------------------------------------------------------------------
__global__ __launch_bounds__(256) void transpose_kernel(const _Float16* __restrict__ in,
                                                        _Float16* __restrict__ out) {
  __shared__ _Float16 tile[32][33];
  const int plane = blockIdx.z;
  const int d0 = blockIdx.x * 32, s0 = blockIdx.y * 32;
  const int tx = threadIdx.x & 31, ty = threadIdx.x >> 5;
  const _Float16* ip = in + (size_t)plane * S_ * D_;
  _Float16* op = out + (size_t)plane * S_ * D_;
#pragma unroll
  for (int i = 0; i < 4; ++i)
    tile[ty + i * 8][tx] = ip[(size_t)(s0 + ty + i * 8) * D_ + d0 + tx];
  __syncthreads();
#pragma unroll
  for (int i = 0; i < 4; ++i)
    op[(size_t)(d0 + ty + i * 8) * S_ + s0 + tx] = tile[tx][ty + i * 8];
}

// ---------------------------------------------------------------------------
// Fused flash attention. Block = (b,h, 64 q-rows); 4 waves x 16 rows.
// T-tiles of 64: QK^T -> (+pb)/sqrtD +mask +prev -> scores out (f32) ->
// online softmax -> P (f16, LDS per-wave) -> PV -> ctx f16 (B,S,HID).
// ---------------------------------------------------------------------------
__global__ __launch_bounds__(256) void flash_kernel(
    const _Float16* __restrict__ q, const _Float16* __restrict__ k,
    const _Float16* __restrict__ vt, const float* __restrict__ pbias,
    const float* __restrict__ maskp, const float* __restrict__ prev,
    float* __restrict__ scores, _Float16* __restrict__ ctx) {
  constexpr int BT = 64;
  __shared__ _Float16 Ks[BT * D_];    // [t][d]  16 KB
  __shared__ _Float16 VTs[D_ * BT];   // [d][t]  16 KB
  __shared__ _Float16 Ps[4][16 * BT]; // per-wave P  8 KB

  const int tid = threadIdx.x, w = tid >> 6, l = tid & 63;
  const int lr = l & 15, lh = l >> 4;
  const int byh = blockIdx.y;
  const int b = byh >> 4, h = byh & 15;
  const size_t plane = (size_t)byh;
  const int q0 = blockIdx.x * 64 + w * 16;

  // Q A-fragments (rows q0..q0+15, all D=128)
  f16x8 qa[4];
#pragma unroll
  for (int kk = 0; kk < 4; ++kk)
    qa[kk] = *(const f16x8*)(q + (plane * S_ + q0 + lr) * D_ + kk * 32 + lh * 8);

  f32x4 o[8] = {};
  float m_r[4], l_r[4];
#pragma unroll
  for (int r = 0; r < 4; ++r) { m_r[r] = -1e30f; l_r[r] = 0.0f; }

  for (int tt = 0; tt < S_ / BT; ++tt) {
    const int t0 = tt * BT;
    __syncthreads();
#pragma unroll
    for (int i = 0; i < 4; ++i) {
      const int e = i * 2048 + tid * 8;
      gll16(k + (plane * S_ + t0 + (e >> 7)) * D_ + (e & 127), Ks + e);
      gll16(vt + (plane * D_ + (e >> 6)) * S_ + t0 + (e & 63), VTs + e);
    }
    asm volatile("s_waitcnt vmcnt(0)" ::: "memory");
    __syncthreads();

    // QK^T : 4 t-frags x 4 k-steps
    f32x4 sa[4] = {};
#pragma unroll
    for (int nt = 0; nt < 4; ++nt)
#pragma unroll
      for (int kk = 0; kk < 4; ++kk) {
        f16x8 kb = *(const f16x8*)(Ks + (nt * 16 + lr) * D_ + kk * 32 + lh * 8);
        sa[nt] = MFMA16(qa[kk], kb, sa[nt]);
      }

    // epilogue: score = (qk + pb)/sqrt(D) + mask + prev ; write scores
    float p[4][4];
    const int srow_base = q0 + lh * 4;
#pragma unroll
    for (int nt = 0; nt < 4; ++nt) {
      const int t = t0 + nt * 16 + lr;
#pragma unroll
      for (int r = 0; r < 4; ++r) {
        const int srow = srow_base + r;
        const size_t idx = (plane * S_ + srow) * S_ + t;
        float sc = (sa[nt][r] + pbias[((size_t)(h * S_ + srow)) * S_ + t]) * RSQRT_D
                 + maskp[((size_t)(b * S_ + srow)) * S_ + t] + prev[idx];
        scores[idx] = sc;
        p[nt][r] = sc;
      }
    }

    // online softmax (rows live in 16-lane groups; reduce over nt + lanes 0..15)
#pragma unroll
    for (int r = 0; r < 4; ++r) {
      float tm = fmaxf(fmaxf(p[0][r], p[1][r]), fmaxf(p[2][r], p[3][r]));
      tm = fmaxf(tm, __shfl_xor(tm, 1));
      tm = fmaxf(tm, __shfl_xor(tm, 2));
      tm = fmaxf(tm, __shfl_xor(tm, 4));
      tm = fmaxf(tm, __shfl_xor(tm, 8));
      const float newm = fmaxf(m_r[r], tm);
      const float al = __expf(m_r[r] - newm);
      float ts = 0.0f;
#pragma unroll
      for (int nt = 0; nt < 4; ++nt) { p[nt][r] = __expf(p[nt][r] - newm); ts += p[nt][r]; }
      ts += __shfl_xor(ts, 1);
      ts += __shfl_xor(ts, 2);
      ts += __shfl_xor(ts, 4);
      ts += __shfl_xor(ts, 8);
      l_r[r] = l_r[r] * al + ts;
      m_r[r] = newm;
#pragma unroll
      for (int nd = 0; nd < 8; ++nd) o[nd][r] *= al;
    }

    // P -> per-wave LDS (C-layout -> [row][t]) then read as A-frags
    _Float16* pw = &Ps[w][0];
#pragma unroll
    for (int nt = 0; nt < 4; ++nt)
#pragma unroll
      for (int r = 0; r < 4; ++r)
        pw[(lh * 4 + r) * BT + nt * 16 + lr] = (_Float16)p[nt][r];
    asm volatile("s_waitcnt lgkmcnt(0)" ::: "memory");

#pragma unroll
    for (int kk2 = 0; kk2 < 2; ++kk2) {
      f16x8 pa = *(const f16x8*)(pw + lr * BT + kk2 * 32 + lh * 8);
#pragma unroll
      for (int nd = 0; nd < 8; ++nd) {
        f16x8 vb = *(const f16x8*)(VTs + (nd * 16 + lr) * BT + kk2 * 32 + lh * 8);
        o[nd] = MFMA16(pa, vb, o[nd]);
      }
    }
  }

  // ctx (B,S,HID) f16
#pragma unroll
  for (int nd = 0; nd < 8; ++nd) {
    const int d = nd * 16 + lr;
#pragma unroll
    for (int r = 0; r < 4; ++r) {
      const int srow = q0 + lh * 4 + r;
      ctx[((size_t)(b * S_ + srow)) * HID_ + h * D_ + d] = (_Float16)(o[nd][r] / l_r[r]);
    }
  }
}

// ---------------------------------------------------------------------------
extern "C" void kernel_launch(void* const* d_in, const int* in_sizes, int n_in,
                              void* d_out, int out_size, void* d_ws, size_t ws_size,
                              hipStream_t stream) {
  const float* query = (const float*)d_in[0];
  const float* key_i = (const float*)d_in[1];
  const float* value = (const float*)d_in[2];
  const float* maskp = (const float*)d_in[3];
  const float* pbias = (const float*)d_in[4];
  const float* prev  = (const float*)d_in[5];
  const int*   pids  = (const int*)d_in[6];
  const float* Wq = (const float*)d_in[7];
  const float* bq = (const float*)d_in[8];
  const float* Wk = (const float*)d_in[9];
  const float* bk = (const float*)d_in[10];
  const float* Wv = (const float*)d_in[11];
  const float* bv = (const float*)d_in[12];
  const float* Wo = (const float*)d_in[13];
  const float* bo = (const float*)d_in[14];

  char* ws = (char*)d_ws;
  // workspace layout (bytes); total need = 134,479,872
  const size_t OFF_TCOS = 0;
  const size_t OFF_TSIN = 131072;
  const size_t OFF_W    = 262144;                      // 4 x 8 MB f16 weights
  const size_t OFF_X    = OFF_W + 4ull * 8388608;      // 3 x 16 MB f16 X
  const size_t OFF_Q    = OFF_X + 3ull * 16777216;
  const size_t OFF_K    = OFF_Q + 16777216;
  const size_t OFF_V    = OFF_K + 16777216;
  const size_t OFF_VT   = OFF_X;                        // reuse Xq (consumed)
  const size_t OFF_CTX  = OFF_X + 16777216;             // reuse Xk (consumed)

  float* tcos = (float*)(ws + OFF_TCOS);
  float* tsin = (float*)(ws + OFF_TSIN);
  _Float16* Wq16 = (_Float16*)(ws + OFF_W);
  _Float16* Wk16 = (_Float16*)(ws + OFF_W + 8388608);
  _Float16* Wv16 = (_Float16*)(ws + OFF_W + 2ull * 8388608);
  _Float16* Wo16 = (_Float16*)(ws + OFF_W + 3ull * 8388608);
  _Float16* Xq16 = (_Float16*)(ws + OFF_X);
  _Float16* Xk16 = (_Float16*)(ws + OFF_X + 16777216);
  _Float16* Xv16 = (_Float16*)(ws + OFF_X + 2ull * 16777216);
  _Float16* q16  = (_Float16*)(ws + OFF_Q);
  _Float16* k16  = (_Float16*)(ws + OFF_K);
  _Float16* v16  = (_Float16*)(ws + OFF_V);
  _Float16* vt16 = (_Float16*)(ws + OFF_VT);
  _Float16* ctx16 = (_Float16*)(ws + OFF_CTX);

  float* out_f32 = (float*)d_out;                 // (B,S,HID) = 8,388,608
  float* scores  = (float*)d_out + 8388608;       // (B,H,S,S) = 67,108,864

  rope_table_kernel<<<128, 256, 0, stream>>>(tcos, tsin);

  cvt_kernel<<<2048, 256, 0, stream>>>(Wq, Wq16, 524288);
  cvt_kernel<<<2048, 256, 0, stream>>>(Wk, Wk16, 524288);
  cvt_kernel<<<2048, 256, 0, stream>>>(Wv, Wv16, 524288);
  cvt_kernel<<<2048, 256, 0, stream>>>(Wo, Wo16, 524288);
  cvt_kernel<<<4096, 256, 0, stream>>>(query, Xq16, 1048576);
  cvt_kernel<<<4096, 256, 0, stream>>>(key_i, Xk16, 1048576);
  cvt_kernel<<<4096, 256, 0, stream>>>(value, Xv16, 1048576);

  proj_kernel<0><<<512, 256, 0, stream>>>(Xq16, Wq16, bq, (void*)q16, pids, tcos, tsin);
  proj_kernel<0><<<512, 256, 0, stream>>>(Xk16, Wk16, bk, (void*)k16, pids, tcos, tsin);
  proj_kernel<1><<<512, 256, 0, stream>>>(Xv16, Wv16, bv, (void*)v16, nullptr, nullptr, nullptr);

  transpose_kernel<<<dim3(4, 32, 64), 256, 0, stream>>>(v16, vt16);

  flash_kernel<<<dim3(16, 64), 256, 0, stream>>>(q16, k16, vt16, pbias, maskp, prev,
                                                 scores, ctx16);

  proj_kernel<2><<<512, 256, 0, stream>>>(ctx16, Wo16, bo, (void*)out_f32,
                                          nullptr, nullptr, nullptr);
}